// Round 2
// baseline (182.545 us; speedup 1.0000x reference)
//
#include <hip/hip_runtime.h>
#include <stdint.h>

// y[b,r] = sum_t x[b, idx[r,t]] * w[r,t] - bias[r]
// fp32 x (1024x4096), fp32 w (8192x32), fp32 bias (8192), int32 idx (8192x32), fp32 out (1024x8192)

#define IN_DIM   4096
#define OUT_DIM  8192
#define BATCH    1024
#define NACT     32
#define R_TILE   64
#define B_TILE   128

__device__ __forceinline__ float bf2f(ushort u) {
    union { uint32_t i; float f; } v; v.i = ((uint32_t)u) << 16; return v.f;
}
__device__ __forceinline__ ushort f2bf(float f) {
    union { float f; uint32_t i; } v; v.f = f;
    uint32_t b = v.i + 0x7fffu + ((v.i >> 16) & 1u);   // RNE
    return (ushort)(b >> 16);
}

// ---- x (1024 x 4096 fp32) -> xT (4096 x 1024 bf16) ----
__global__ __launch_bounds__(256) void transpose_to_bf16(const float* __restrict__ x,
                                                         uint32_t* __restrict__ xT32) {
    __shared__ float tile[64][65];
    const int tx = threadIdx.x & 63, ty0 = threadIdx.x >> 6;
    const int c0 = blockIdx.x * 64, b0 = blockIdx.y * 64;
#pragma unroll
    for (int k = 0; k < 16; ++k) {
        int b = ty0 + k * 4;
        tile[b][tx] = x[(size_t)(b0 + b) * IN_DIM + c0 + tx];
    }
    __syncthreads();
    // write xT rows: 64 c-rows x 32 uint32 (2 bf16 batches each)
#pragma unroll
    for (int k = 0; k < 8; ++k) {
        int lin = k * 256 + threadIdx.x;
        int c = lin >> 5, bp = lin & 31;
        ushort u0 = f2bf(tile[2 * bp][c]);
        ushort u1 = f2bf(tile[2 * bp + 1][c]);
        xT32[(size_t)(c0 + c) * (BATCH / 2) + (b0 >> 1) + bp] = u0 | ((uint32_t)u1 << 16);
    }
}

// ---- main: one block = 64 rows x 128 batches; lane = 2 batches; wave = 16 rows ----
template <bool USE_XT>
__global__ __launch_bounds__(256, 4) void sparse_mm(const void*  __restrict__ xsrc,  // xT (bf16) or x (fp32)
                                                    const int*   __restrict__ idx,
                                                    const float* __restrict__ w,
                                                    const float* __restrict__ bias,
                                                    float*       __restrict__ out) {
    const int bid = blockIdx.x;
    const int bchunk = bid & 7;       // XCD round-robin: pin batch chunk -> XCD L2
    const int rtile  = bid >> 3;
    const int r0 = rtile * R_TILE, b0 = bchunk * B_TILE;
    const int tid = threadIdx.x, wave = tid >> 6, lane = tid & 63;

    // detect int64-layout idx (all odd dwords zero); uniform branch
    const uint32_t* gi = (const uint32_t*)idx;
    const bool idx64 = ((gi[1] | gi[3] | gi[5] | gi[7] | gi[9] | gi[11] | gi[13] | gi[15]) == 0u);

    const uint32_t* xb = (const uint32_t*)xsrc + (b0 >> 1) + lane;  // bf16-pair view (USE_XT)
    const float*    xf = (const float*)xsrc;                        // fallback fp32 view

#pragma unroll 1
    for (int g = 0; g < 4; ++g) {
        const int rb = r0 + wave * 16 + g * 4;   // rows rb..rb+3
        float a0[4], a1[4];
#pragma unroll
        for (int k = 0; k < 4; ++k) { float bv = bias[rb + k]; a0[k] = -bv; a1[k] = -bv; }

#pragma unroll
        for (int k = 0; k < 4; ++k) {
            int ci[NACT];
            if (!idx64) {
                const int4* ir = (const int4*)(idx + (size_t)(rb + k) * NACT);
#pragma unroll
                for (int q = 0; q < 8; ++q) {
                    int4 ii = ir[q];
                    ci[4 * q] = ii.x; ci[4 * q + 1] = ii.y; ci[4 * q + 2] = ii.z; ci[4 * q + 3] = ii.w;
                }
            } else {
                const int4* ir = (const int4*)((const char*)idx + (size_t)(rb + k) * NACT * 8);
#pragma unroll
                for (int q = 0; q < 16; ++q) {
                    int4 ii = ir[q];
                    ci[2 * q] = ii.x; ci[2 * q + 1] = ii.z;
                }
            }
            const float4* wr = (const float4*)(w + (size_t)(rb + k) * NACT);
#pragma unroll
            for (int q = 0; q < 8; ++q) {
                float4 wf = wr[q];
                float wv[4] = {wf.x, wf.y, wf.z, wf.w};
#pragma unroll
                for (int u = 0; u < 4; ++u) {
                    const int c = ci[4 * q + u];
                    if (USE_XT) {
                        uint32_t v = xb[(uint32_t)c << 9];   // c*512 words; coalesced 256B/wave
                        a0[k] = fmaf(bf2f((ushort)(v & 0xffffu)), wv[u], a0[k]);
                        a1[k] = fmaf(bf2f((ushort)(v >> 16)),     wv[u], a1[k]);
                    } else {
                        float e0 = xf[(size_t)(b0 + 2 * lane)     * IN_DIM + c];
                        float e1 = xf[(size_t)(b0 + 2 * lane + 1) * IN_DIM + c];
                        a0[k] = fmaf(e0, wv[u], a0[k]);
                        a1[k] = fmaf(e1, wv[u], a1[k]);
                    }
                }
            }
        }
        float4 s0 = make_float4(a0[0], a0[1], a0[2], a0[3]);
        float4 s1 = make_float4(a1[0], a1[1], a1[2], a1[3]);
        *(float4*)&out[(size_t)(b0 + 2 * lane)     * OUT_DIM + rb] = s0;   // 16B aligned (rb%4==0)
        *(float4*)&out[(size_t)(b0 + 2 * lane + 1) * OUT_DIM + rb] = s1;
    }
}

extern "C" void kernel_launch(void* const* d_in, const int* in_sizes, int n_in,
                              void* d_out, int out_size, void* d_ws, size_t ws_size,
                              hipStream_t stream) {
    const float* x    = (const float*)d_in[0];
    const float* wk   = (const float*)d_in[1];
    const float* bias = (const float*)d_in[2];
    const int*   idx  = (const int*)d_in[3];
    float*       out  = (float*)d_out;

    const size_t xT_bytes = (size_t)IN_DIM * BATCH * 2;   // 8 MB bf16
    const int nblocks = (OUT_DIM / R_TILE) * (BATCH / B_TILE);   // 128*8 = 1024
    if (ws_size >= xT_bytes) {
        uint32_t* xT32 = (uint32_t*)d_ws;
        transpose_to_bf16<<<dim3(IN_DIM / 64, BATCH / 64), 256, 0, stream>>>(x, xT32);
        sparse_mm<true><<<nblocks, 256, 0, stream>>>((const void*)xT32, idx, wk, bias, out);
    } else {
        sparse_mm<false><<<nblocks, 256, 0, stream>>>((const void*)x, idx, wk, bias, out);
    }
}

// Round 3
// 168.491 us; speedup vs baseline: 1.0834x; 1.0834x over previous
//
#include <hip/hip_runtime.h>
#include <stdint.h>

// y[b,r] = sum_t x[b, idx[r,t]] * w[r,t] - bias[r]
// fp32 x (1024x4096), fp32 w (8192x32), fp32 bias (8192), int32 idx (8192x32), fp32 out (1024x8192)

#define IN_DIM   4096
#define OUT_DIM  8192
#define BATCH    1024
#define NACT     32
#define R_TILE   64
#define B_TILE   128

typedef float f4v __attribute__((ext_vector_type(4)));

__device__ __forceinline__ float bf2f(ushort u) {
    union { uint32_t i; float f; } v; v.i = ((uint32_t)u) << 16; return v.f;
}
__device__ __forceinline__ ushort f2bf(float f) {
    union { float f; uint32_t i; } v; v.f = f;
    uint32_t b = v.i + 0x7fffu + ((v.i >> 16) & 1u);   // RNE
    return (ushort)(b >> 16);
}

// ---- x (1024 x 4096 fp32) -> xT (4096 x 1024 bf16) ----
__global__ __launch_bounds__(256) void transpose_to_bf16(const float* __restrict__ x,
                                                         uint32_t* __restrict__ xT32) {
    __shared__ float tile[64][65];
    const int tx = threadIdx.x & 63, ty0 = threadIdx.x >> 6;
    const int c0 = blockIdx.x * 64, b0 = blockIdx.y * 64;
#pragma unroll
    for (int k = 0; k < 16; ++k) {
        int b = ty0 + k * 4;
        tile[b][tx] = x[(size_t)(b0 + b) * IN_DIM + c0 + tx];
    }
    __syncthreads();
#pragma unroll
    for (int k = 0; k < 8; ++k) {
        int lin = k * 256 + threadIdx.x;
        int c = lin >> 5, bp = lin & 31;
        ushort u0 = f2bf(tile[2 * bp][c]);
        ushort u1 = f2bf(tile[2 * bp + 1][c]);
        xT32[(size_t)(c0 + c) * (BATCH / 2) + (b0 >> 1) + bp] = u0 | ((uint32_t)u1 << 16);
    }
}

// ---- main: one block = 64 rows x 128 batches; lane = 2 batches; wave = 16 rows ----
template <bool USE_XT>
__global__ __launch_bounds__(256, 4) void sparse_mm(const void*  __restrict__ xsrc,
                                                    const int*   __restrict__ idx,
                                                    const float* __restrict__ w,
                                                    const float* __restrict__ bias,
                                                    float*       __restrict__ out) {
    __shared__ float s_out[B_TILE][R_TILE + 1];   // [128][65] = 33.3 KB, 2-way banks both phases

    const int bid = blockIdx.x;
    const int bchunk = bid & 7;       // XCD round-robin pin: batch chunk -> XCD L2
    const int rtile  = bid >> 3;
    const int r0 = rtile * R_TILE, b0 = bchunk * B_TILE;
    const int tid = threadIdx.x, wave = tid >> 6, lane = tid & 63;

    // detect int64-layout idx (all odd dwords zero); uniform branch
    const uint32_t* gi = (const uint32_t*)idx;
    const bool idx64 = ((gi[1] | gi[3] | gi[5] | gi[7] | gi[9] | gi[11] | gi[13] | gi[15]) == 0u);

    const uint32_t* xb = (const uint32_t*)xsrc + (b0 >> 1) + lane;  // bf16-pair view (USE_XT)
    const float*    xf = (const float*)xsrc;                        // fallback fp32 view

#pragma unroll 1
    for (int g = 0; g < 4; ++g) {
        const int rl = wave * 16 + g * 4;        // local rows rl..rl+3
        const int rb = r0 + rl;
        float a0[4], a1[4];
#pragma unroll
        for (int k = 0; k < 4; ++k) { float bv = bias[rb + k]; a0[k] = -bv; a1[k] = -bv; }

#pragma unroll
        for (int k = 0; k < 4; ++k) {
            int ci[NACT];
            if (!idx64) {
                const int4* ir = (const int4*)(idx + (size_t)(rb + k) * NACT);
#pragma unroll
                for (int q = 0; q < 8; ++q) {
                    int4 ii = ir[q];
                    ci[4 * q] = ii.x; ci[4 * q + 1] = ii.y; ci[4 * q + 2] = ii.z; ci[4 * q + 3] = ii.w;
                }
            } else {
                const int4* ir = (const int4*)((const char*)idx + (size_t)(rb + k) * NACT * 8);
#pragma unroll
                for (int q = 0; q < 16; ++q) {
                    int4 ii = ir[q];
                    ci[2 * q] = ii.x; ci[2 * q + 1] = ii.z;
                }
            }
            const float4* wr = (const float4*)(w + (size_t)(rb + k) * NACT);
#pragma unroll
            for (int q = 0; q < 8; ++q) {
                float4 wf = wr[q];
                float wv[4] = {wf.x, wf.y, wf.z, wf.w};
#pragma unroll
                for (int u = 0; u < 4; ++u) {
                    const int c = ci[4 * q + u];
                    if (USE_XT) {
                        uint32_t v = xb[(uint32_t)c << 9];   // wave reads 256B contiguous
                        a0[k] = fmaf(bf2f((ushort)(v & 0xffffu)), wv[u], a0[k]);
                        a1[k] = fmaf(bf2f((ushort)(v >> 16)),     wv[u], a1[k]);
                    } else {
                        float e0 = xf[(size_t)(b0 + 2 * lane)     * IN_DIM + c];
                        float e1 = xf[(size_t)(b0 + 2 * lane + 1) * IN_DIM + c];
                        a0[k] = fmaf(e0, wv[u], a0[k]);
                        a1[k] = fmaf(e1, wv[u], a1[k]);
                    }
                }
            }
        }
        // stage to LDS: bank = (2*lane + rl + k) % 32 -> 2-way (free)
#pragma unroll
        for (int k = 0; k < 4; ++k) {
            s_out[2 * lane    ][rl + k] = a0[k];
            s_out[2 * lane + 1][rl + k] = a1[k];
        }
    }
    __syncthreads();

    // coalesced epilogue: each wave stores 4 batches x 256B contiguous (full lines)
#pragma unroll
    for (int it = 0; it < 8; ++it) {
        int lin = it * 256 + tid;            // 2048 float4 in tile
        int b  = lin >> 4;                   // 128 rows
        int rp = lin & 15;                   // 16 float4 per row
        f4v v;
        v.x = s_out[b][4 * rp + 0];
        v.y = s_out[b][4 * rp + 1];
        v.z = s_out[b][4 * rp + 2];
        v.w = s_out[b][4 * rp + 3];
        f4v* p = (f4v*)&out[(size_t)(b0 + b) * OUT_DIM + r0 + 4 * rp];
        __builtin_nontemporal_store(v, p);
    }
}

extern "C" void kernel_launch(void* const* d_in, const int* in_sizes, int n_in,
                              void* d_out, int out_size, void* d_ws, size_t ws_size,
                              hipStream_t stream) {
    const float* x    = (const float*)d_in[0];
    const float* wk   = (const float*)d_in[1];
    const float* bias = (const float*)d_in[2];
    const int*   idx  = (const int*)d_in[3];
    float*       out  = (float*)d_out;

    const size_t xT_bytes = (size_t)IN_DIM * BATCH * 2;              // 8 MB bf16
    const int nblocks = (OUT_DIM / R_TILE) * (BATCH / B_TILE);       // 1024
    if (ws_size >= xT_bytes) {
        uint32_t* xT32 = (uint32_t*)d_ws;
        transpose_to_bf16<<<dim3(IN_DIM / 64, BATCH / 64), 256, 0, stream>>>(x, xT32);
        sparse_mm<true><<<nblocks, 256, 0, stream>>>((const void*)xT32, idx, wk, bias, out);
    } else {
        sparse_mm<false><<<nblocks, 256, 0, stream>>>((const void*)x, idx, wk, bias, out);
    }
}